// Round 9
// baseline (496.227 us; speedup 1.0000x reference)
//
#include <hip/hip_runtime.h>
#include <hip/hip_bf16.h>
#include <math.h>

// Problem constants (match reference setup_inputs()).
#define N_NODES 20000
#define N_EDGES 320000
#define N_GRAPHS 64
#define SEQ 20
#define SCALAR 16
#define EMB 32
#define HID 128
#define IN_DIM 176         // SCALAR + 5*EMB
#define TOT_EDGES (N_EDGES + N_NODES)  // with self loops
#define CHUNK_SMALL 10000  // fallback node chunk when workspace is tight

__device__ inline float readlane_f(float v, int l) {
  return __uint_as_float(__builtin_amdgcn_readlane(__float_as_uint(v), l));
}
__device__ inline int readlane_i(int v, int l) {
  return __builtin_amdgcn_readlane(v, l);
}
__device__ inline float leaky(float e) { return e >= 0.f ? e : 0.2f * e; }
__device__ inline float elu(float v) { return v > 0.f ? v : expf(v) - 1.f; }

// ---------------------------------------------------------------------------
// Kernel 1: feats = concat(scalar, 5x masked-mean-embed) ; LayerNorm -> h
// ---------------------------------------------------------------------------
__global__ __launch_bounds__(192) void feats_ln_kernel(
    const float* __restrict__ xs,
    const int* __restrict__ i0, const int* __restrict__ i1,
    const int* __restrict__ i2, const int* __restrict__ i3,
    const int* __restrict__ i4,
    const float* __restrict__ t0, const float* __restrict__ t1,
    const float* __restrict__ t2, const float* __restrict__ t3,
    const float* __restrict__ t4,
    const float* __restrict__ gamma, const float* __restrict__ beta,
    float* __restrict__ hout) {
  int n = blockIdx.x, t = threadIdx.x;
  __shared__ int sidx[5][SEQ];
  __shared__ float sf[IN_DIM];
  __shared__ float s_mu, s_rstd;
  if (t < 5 * SEQ) {
    int tab = t / SEQ, l = t % SEQ;
    const int* ip = tab == 0 ? i0 : tab == 1 ? i1 : tab == 2 ? i2 : tab == 3 ? i3 : i4;
    sidx[tab][l] = ip[n * SEQ + l];
  }
  __syncthreads();
  float f = 0.f;
  if (t < SCALAR) {
    f = xs[n * SCALAR + t];
  } else if (t < IN_DIM) {
    int tt = t - SCALAR, tab = tt >> 5, d = tt & 31;
    const float* tp = tab == 0 ? t0 : tab == 1 ? t1 : tab == 2 ? t2 : tab == 3 ? t3 : t4;
    float sum = 0.f, cnt = 0.f;
#pragma unroll
    for (int l = 0; l < SEQ; ++l) {
      int id = sidx[tab][l];
      if (id != 0) { sum += tp[id * EMB + d]; cnt += 1.f; }
    }
    f = sum / (cnt + 1e-9f);
  }
  if (t < IN_DIM) sf[t] = f;
  __syncthreads();
  if (t < 64) {
    float s = 0.f;
    for (int i = t; i < IN_DIM; i += 64) s += sf[i];
    for (int off = 32; off; off >>= 1) s += __shfl_down(s, off);
    if (t == 0) s_mu = s / (float)IN_DIM;
  }
  __syncthreads();
  float mu = s_mu;
  if (t < 64) {
    float s = 0.f;
    for (int i = t; i < IN_DIM; i += 64) { float d2 = sf[i] - mu; s += d2 * d2; }
    for (int off = 32; off; off >>= 1) s += __shfl_down(s, off);
    if (t == 0) s_rstd = 1.0f / sqrtf(s / (float)IN_DIM + 1e-5f);
  }
  __syncthreads();
  if (t < IN_DIM) hout[n * IN_DIM + t] = (f - mu) * s_rstd * gamma[t] + beta[t];
}

// ---------------------------------------------------------------------------
// CSR build.
// ---------------------------------------------------------------------------
__global__ void count_kernel(const int* __restrict__ edge_index,
                             int* __restrict__ cnt, int E, int N) {
  int i = blockIdx.x * blockDim.x + threadIdx.x;
  if (i < E) {
    atomicAdd(&cnt[edge_index[E + i]], 1);
  } else if (i < E + N) {
    atomicAdd(&cnt[i - E], 1);  // self loop dst = node
  }
}

__global__ __launch_bounds__(256) void prefix_kernel(const int* __restrict__ cnt,
                                                     int* __restrict__ indptr,
                                                     int n, int total) {
  __shared__ int ssum[256];
  int t = threadIdx.x;
  int per = (n + 255) / 256;
  int beg = t * per, end = min(beg + per, n);
  int s = 0;
  for (int i = beg; i < end; ++i) s += cnt[i];
  ssum[t] = s;
  __syncthreads();
  if (t == 0) {
    int run = 0;
    for (int i = 0; i < 256; ++i) { int v = ssum[i]; ssum[i] = run; run += v; }
  }
  __syncthreads();
  int run = ssum[t];
  for (int i = beg; i < end; ++i) { indptr[i] = run; run += cnt[i]; }
  if (t == 0) indptr[n] = total;
}

__global__ void scatter_kernel(const int* __restrict__ edge_index,
                               const int* __restrict__ indptr,
                               int* __restrict__ cursor,
                               int* __restrict__ srcs, int E, int N) {
  int i = blockIdx.x * blockDim.x + threadIdx.x;
  int s, d;
  if (i < E) { s = edge_index[i]; d = edge_index[E + i]; }
  else if (i < E + N) { s = i - E; d = s; }
  else return;
  int pos = indptr[d] + atomicAdd(&cursor[d], 1);
  srcs[pos] = s;
}

// ---------------------------------------------------------------------------
// was/wad precompute, wave-per-k: was[k][h] = sum_c W1[k,h*128+c]*att_s[h*128+c].
// ---------------------------------------------------------------------------
__global__ __launch_bounds__(256) void wasd_kernel(
    const float* __restrict__ W1, const float* __restrict__ att_s,
    const float* __restrict__ att_d, float* __restrict__ was4,
    float* __restrict__ wad4) {
  int lane = threadIdx.x & 63;
  int k = blockIdx.x * 4 + (threadIdx.x >> 6);
  if (k >= IN_DIM) return;
  const float* wrow = W1 + (size_t)k * 512;
  float s[4], d[4];
#pragma unroll
  for (int hh = 0; hh < 4; ++hh) {
    float w0 = wrow[hh * 128 + lane], w1 = wrow[hh * 128 + 64 + lane];
    float a0 = att_s[hh * 128 + lane], a1 = att_s[hh * 128 + 64 + lane];
    float c0 = att_d[hh * 128 + lane], c1 = att_d[hh * 128 + 64 + lane];
    s[hh] = w0 * a0 + w1 * a1;
    d[hh] = w0 * c0 + w1 * c1;
  }
  for (int off = 1; off < 64; off <<= 1) {
#pragma unroll
    for (int hh = 0; hh < 4; ++hh) {
      s[hh] += __shfl_xor(s[hh], off);
      d[hh] += __shfl_xor(d[hh], off);
    }
  }
  if (lane == 0) {
    *(float4*)&was4[k * 4] = make_float4(s[0], s[1], s[2], s[3]);
    *(float4*)&wad4[k * 4] = make_float4(d[0], d[1], d[2], d[3]);
  }
}

// ---------------------------------------------------------------------------
// Attention logits layer 1 from h. Wave-per-node (4 nodes / block).
// ---------------------------------------------------------------------------
__global__ __launch_bounds__(256) void att1h_kernel(
    const float* __restrict__ h, const float* __restrict__ was4,
    const float* __restrict__ wad4, float* __restrict__ a_s,
    float* __restrict__ a_d) {
  int lane = threadIdx.x & 63;
  int n = blockIdx.x * 4 + (threadIdx.x >> 6);
  if (n >= N_NODES) return;
  const float* hr = h + (size_t)n * IN_DIM;
  bool l48 = lane < 48;
  float v0 = hr[lane];
  float v1 = hr[64 + lane];
  float v2 = l48 ? hr[128 + lane] : 0.f;
  const float4* wsv = (const float4*)was4;
  const float4* wdv = (const float4*)wad4;
  float4 wsa = wsv[lane], wsb = wsv[64 + lane];
  float4 wsc = l48 ? wsv[128 + lane] : make_float4(0.f, 0.f, 0.f, 0.f);
  float4 wda = wdv[lane], wdb = wdv[64 + lane];
  float4 wdc = l48 ? wdv[128 + lane] : make_float4(0.f, 0.f, 0.f, 0.f);
  float ps0 = v0 * wsa.x + v1 * wsb.x + v2 * wsc.x;
  float ps1 = v0 * wsa.y + v1 * wsb.y + v2 * wsc.y;
  float ps2 = v0 * wsa.z + v1 * wsb.z + v2 * wsc.z;
  float ps3 = v0 * wsa.w + v1 * wsb.w + v2 * wsc.w;
  float pd0 = v0 * wda.x + v1 * wdb.x + v2 * wdc.x;
  float pd1 = v0 * wda.y + v1 * wdb.y + v2 * wdc.y;
  float pd2 = v0 * wda.z + v1 * wdb.z + v2 * wdc.z;
  float pd3 = v0 * wda.w + v1 * wdb.w + v2 * wdc.w;
  for (int off = 1; off < 64; off <<= 1) {
    ps0 += __shfl_xor(ps0, off); ps1 += __shfl_xor(ps1, off);
    ps2 += __shfl_xor(ps2, off); ps3 += __shfl_xor(ps3, off);
    pd0 += __shfl_xor(pd0, off); pd1 += __shfl_xor(pd1, off);
    pd2 += __shfl_xor(pd2, off); pd3 += __shfl_xor(pd3, off);
  }
  if (lane == 0) {
    *(float4*)&a_s[n * 4] = make_float4(ps0, ps1, ps2, ps3);
    *(float4*)&a_d[n * 4] = make_float4(pd0, pd1, pd2, pd3);
  }
}

// ---------------------------------------------------------------------------
// Layer-1 softmax + aggregate h (176-dim) per head -> aggh[(ln*4+h)*176+k].
// Wave-per-node, zero barriers. Nodes [n0, n0+nM).
// ---------------------------------------------------------------------------
__global__ __launch_bounds__(256) void agg1h_kernel(
    const float* __restrict__ h, const float* __restrict__ a_src,
    const float* __restrict__ a_dst, const int* __restrict__ indptr,
    const int* __restrict__ srcs, float* __restrict__ aggh,
    int n0, int nM) {
  int lane = threadIdx.x & 63;
  int ln = blockIdx.x * 4 + (threadIdx.x >> 6);
  if (ln >= nM) return;
  int n = n0 + ln;
  int beg = indptr[n], end = indptr[n + 1];
  int deg = end - beg;
  float4 ad = *(const float4*)&a_dst[n * 4];
  bool l48 = lane < 48;
  float acc[4][3] = {};

  auto body = [&](int s, float al0, float al1, float al2, float al3) {
    const float* r = h + (size_t)s * IN_DIM;
    float v0 = r[lane];
    float v1 = r[64 + lane];
    float v2 = l48 ? r[128 + lane] : 0.f;
    acc[0][0] += al0 * v0; acc[0][1] += al0 * v1; acc[0][2] += al0 * v2;
    acc[1][0] += al1 * v0; acc[1][1] += al1 * v1; acc[1][2] += al1 * v2;
    acc[2][0] += al2 * v0; acc[2][1] += al2 * v1; acc[2][2] += al2 * v2;
    acc[3][0] += al3 * v0; acc[3][1] += al3 * v1; acc[3][2] += al3 * v2;
  };

  if (deg <= 64) {
    int j = beg + lane;
    int s = 0;
    float e0 = -INFINITY, e1 = -INFINITY, e2 = -INFINITY, e3 = -INFINITY;
    if (j < end) {
      s = srcs[j];
      float4 as = *(const float4*)&a_src[s * 4];
      e0 = leaky(as.x + ad.x); e1 = leaky(as.y + ad.y);
      e2 = leaky(as.z + ad.z); e3 = leaky(as.w + ad.w);
    }
    float m0 = e0, m1 = e1, m2 = e2, m3 = e3;
    for (int off = 1; off < 64; off <<= 1) {
      m0 = fmaxf(m0, __shfl_xor(m0, off)); m1 = fmaxf(m1, __shfl_xor(m1, off));
      m2 = fmaxf(m2, __shfl_xor(m2, off)); m3 = fmaxf(m3, __shfl_xor(m3, off));
    }
    float x0 = (j < end) ? expf(e0 - m0) : 0.f;
    float x1 = (j < end) ? expf(e1 - m1) : 0.f;
    float x2 = (j < end) ? expf(e2 - m2) : 0.f;
    float x3 = (j < end) ? expf(e3 - m3) : 0.f;
    float d0 = x0, d1 = x1, d2 = x2, d3 = x3;
    for (int off = 1; off < 64; off <<= 1) {
      d0 += __shfl_xor(d0, off); d1 += __shfl_xor(d1, off);
      d2 += __shfl_xor(d2, off); d3 += __shfl_xor(d3, off);
    }
    float al0 = x0 / (d0 + 1e-16f), al1 = x1 / (d1 + 1e-16f);
    float al2 = x2 / (d2 + 1e-16f), al3 = x3 / (d3 + 1e-16f);
    int jj = 0;
    for (; jj + 2 <= deg; jj += 2) {
      int sa = readlane_i(s, jj), sb = readlane_i(s, jj + 1);
      float a0 = readlane_f(al0, jj), a1 = readlane_f(al1, jj);
      float a2 = readlane_f(al2, jj), a3 = readlane_f(al3, jj);
      float b0 = readlane_f(al0, jj + 1), b1 = readlane_f(al1, jj + 1);
      float b2 = readlane_f(al2, jj + 1), b3 = readlane_f(al3, jj + 1);
      body(sa, a0, a1, a2, a3);
      body(sb, b0, b1, b2, b3);
    }
    if (jj < deg) {
      int sa = readlane_i(s, jj);
      body(sa, readlane_f(al0, jj), readlane_f(al1, jj),
           readlane_f(al2, jj), readlane_f(al3, jj));
    }
  } else {
    float m0 = -INFINITY, m1 = -INFINITY, m2 = -INFINITY, m3 = -INFINITY;
    for (int j0 = beg; j0 < end; j0 += 64) {
      int j = j0 + lane;
      if (j < end) {
        int s = srcs[j];
        float4 as = *(const float4*)&a_src[s * 4];
        m0 = fmaxf(m0, leaky(as.x + ad.x)); m1 = fmaxf(m1, leaky(as.y + ad.y));
        m2 = fmaxf(m2, leaky(as.z + ad.z)); m3 = fmaxf(m3, leaky(as.w + ad.w));
      }
    }
    for (int off = 1; off < 64; off <<= 1) {
      m0 = fmaxf(m0, __shfl_xor(m0, off)); m1 = fmaxf(m1, __shfl_xor(m1, off));
      m2 = fmaxf(m2, __shfl_xor(m2, off)); m3 = fmaxf(m3, __shfl_xor(m3, off));
    }
    float d0 = 0.f, d1 = 0.f, d2 = 0.f, d3 = 0.f;
    for (int j0 = beg; j0 < end; j0 += 64) {
      int j = j0 + lane;
      if (j < end) {
        int s = srcs[j];
        float4 as = *(const float4*)&a_src[s * 4];
        d0 += expf(leaky(as.x + ad.x) - m0); d1 += expf(leaky(as.y + ad.y) - m1);
        d2 += expf(leaky(as.z + ad.z) - m2); d3 += expf(leaky(as.w + ad.w) - m3);
      }
    }
    for (int off = 1; off < 64; off <<= 1) {
      d0 += __shfl_xor(d0, off); d1 += __shfl_xor(d1, off);
      d2 += __shfl_xor(d2, off); d3 += __shfl_xor(d3, off);
    }
    float r0 = 1.f / (d0 + 1e-16f), r1 = 1.f / (d1 + 1e-16f);
    float r2 = 1.f / (d2 + 1e-16f), r3 = 1.f / (d3 + 1e-16f);
    for (int j0 = beg; j0 < end; j0 += 64) {
      int jn = min(64, end - j0);
      int j = j0 + lane;
      int s = 0;
      float al0 = 0.f, al1 = 0.f, al2 = 0.f, al3 = 0.f;
      if (j < end) {
        s = srcs[j];
        float4 as = *(const float4*)&a_src[s * 4];
        al0 = expf(leaky(as.x + ad.x) - m0) * r0;
        al1 = expf(leaky(as.y + ad.y) - m1) * r1;
        al2 = expf(leaky(as.z + ad.z) - m2) * r2;
        al3 = expf(leaky(as.w + ad.w) - m3) * r3;
      }
      for (int jj = 0; jj < jn; ++jj) {
        body(readlane_i(s, jj), readlane_f(al0, jj), readlane_f(al1, jj),
             readlane_f(al2, jj), readlane_f(al3, jj));
      }
    }
  }

  size_t base = (size_t)ln * (4 * IN_DIM);
#pragma unroll
  for (int hh = 0; hh < 4; ++hh) {
    aggh[base + hh * IN_DIM + lane] = acc[hh][0];
    aggh[base + hh * IN_DIM + 64 + lane] = acc[hh][1];
    if (l48) aggh[base + hh * IN_DIM + 128 + lane] = acc[hh][2];
  }
}

// ---------------------------------------------------------------------------
// Head-GEMM v3 (high block count): out1[n0+r, h*128+col0+c] =
//   ELU(aggh_h[r,:]@W1[:,h*128+col0+c] + b1).
// BM=64, BN=64, BK=16, TM=4, TN=4, grid (2, ceil(M/64), 4) = 2504 blocks.
// ---------------------------------------------------------------------------
__global__ __launch_bounds__(256) void gemm_head_kernel(
    const float* __restrict__ aggh, const float* __restrict__ W1,
    const float* __restrict__ b1, float* __restrict__ out1,
    int M, int n0) {
  const int BM = 64, BN = 64, BK = 16;
  __shared__ float As[BK][BM + 4];
  __shared__ float Bs[BK][BN + 4];
  int tid = threadIdx.x;
  int hh = blockIdx.z;
  int tr = tid >> 4, tc = tid & 15;
  int row0 = blockIdx.y * BM, col0 = blockIdx.x * BN;
  float acc[4][4] = {};
  for (int k0 = 0; k0 < IN_DIM; k0 += BK) {
    {
      int r = tid >> 2, kq = (tid & 3) * 4;  // 256 float4 = BM*BK/4
      int gr = row0 + r;
      float4 v = make_float4(0.f, 0.f, 0.f, 0.f);
      if (gr < M) v = *(const float4*)&aggh[((size_t)gr * 4 + hh) * IN_DIM + k0 + kq];
      As[kq + 0][r] = v.x; As[kq + 1][r] = v.y;
      As[kq + 2][r] = v.z; As[kq + 3][r] = v.w;
    }
    {
      int kk = tid >> 4, cq = (tid & 15) * 4;  // 256 float4 = BK*BN/4
      *(float4*)&Bs[kk][cq] =
          *(const float4*)&W1[(size_t)(k0 + kk) * 512 + hh * 128 + col0 + cq];
    }
    __syncthreads();
#pragma unroll
    for (int kk = 0; kk < BK; ++kk) {
      float a[4], b[4];
      *(float4*)&a[0] = *(const float4*)&As[kk][tr * 4];
      *(float4*)&b[0] = *(const float4*)&Bs[kk][tc * 4];
#pragma unroll
      for (int i = 0; i < 4; ++i)
#pragma unroll
        for (int j = 0; j < 4; ++j) acc[i][j] += a[i] * b[j];
    }
    __syncthreads();
  }
  float4 bv = *(const float4*)&b1[hh * 128 + col0 + tc * 4];
#pragma unroll
  for (int i = 0; i < 4; ++i) {
    int gr = row0 + tr * 4 + i;
    if (gr >= M) continue;
    float4 o;
    o.x = elu(acc[i][0] + bv.x); o.y = elu(acc[i][1] + bv.y);
    o.z = elu(acc[i][2] + bv.z); o.w = elu(acc[i][3] + bv.w);
    *(float4*)&out1[(size_t)(n0 + gr) * 512 + hh * 128 + col0 + tc * 4] = o;
  }
}

// ---------------------------------------------------------------------------
// GEMM2 + fused layer-2 att logits: xw2 = out1@W2; a2s/a2d partial dots via
// 16-lane shfl reduce + one atomicAdd per row-half (a2s/a2d pre-zeroed).
// BM=64, BN=64, BK=16, TM=4, TN=4. grid (2, ceil(M/64)) = 626 blocks.
// ---------------------------------------------------------------------------
__global__ __launch_bounds__(256) void gemm2att_kernel(
    const float* __restrict__ A, const float* __restrict__ W2,
    const float* __restrict__ att_s, const float* __restrict__ att_d,
    float* __restrict__ C, float* __restrict__ a_s, float* __restrict__ a_d,
    int M) {
  const int BM = 64, BN = 64, BK = 16;
  __shared__ float As[BK][BM + 4];
  __shared__ float Bs[BK][BN + 4];
  int tid = threadIdx.x;
  int tr = tid >> 4, tc = tid & 15;
  int row0 = blockIdx.y * BM, col0 = blockIdx.x * BN;
  float acc[4][4] = {};
  for (int k0 = 0; k0 < 512; k0 += BK) {
    {
      int r = tid >> 2, kq = (tid & 3) * 4;  // 256 float4 = BM*BK/4
      int gr = row0 + r;
      float4 v = make_float4(0.f, 0.f, 0.f, 0.f);
      if (gr < M) v = *(const float4*)&A[(size_t)gr * 512 + k0 + kq];
      As[kq + 0][r] = v.x; As[kq + 1][r] = v.y;
      As[kq + 2][r] = v.z; As[kq + 3][r] = v.w;
    }
    {
      int kk = tid >> 4, cq = (tid & 15) * 4;  // 256 float4 = BK*BN/4
      *(float4*)&Bs[kk][cq] = *(const float4*)&W2[(size_t)(k0 + kk) * 128 + col0 + cq];
    }
    __syncthreads();
#pragma unroll
    for (int kk = 0; kk < BK; ++kk) {
      float a[4], b[4];
      *(float4*)&a[0] = *(const float4*)&As[kk][tr * 4];
      *(float4*)&b[0] = *(const float4*)&Bs[kk][tc * 4];
#pragma unroll
      for (int i = 0; i < 4; ++i)
#pragma unroll
        for (int j = 0; j < 4; ++j) acc[i][j] += a[i] * b[j];
    }
    __syncthreads();
  }
  float4 asv = *(const float4*)&att_s[col0 + tc * 4];
  float4 adv = *(const float4*)&att_d[col0 + tc * 4];
#pragma unroll
  for (int i = 0; i < 4; ++i) {
    int gr = row0 + tr * 4 + i;
    if (gr >= M) continue;  // uniform across the 16 tc lanes
    *(float4*)&C[(size_t)gr * 128 + col0 + tc * 4] = *(float4*)&acc[i][0];
    float ps = acc[i][0] * asv.x + acc[i][1] * asv.y +
               acc[i][2] * asv.z + acc[i][3] * asv.w;
    float pd = acc[i][0] * adv.x + acc[i][1] * adv.y +
               acc[i][2] * adv.z + acc[i][3] * adv.w;
    for (int off = 1; off < 16; off <<= 1) {
      ps += __shfl_xor(ps, off);
      pd += __shfl_xor(pd, off);
    }
    if (tc == 0) {
      atomicAdd(&a_s[gr], ps);
      atomicAdd(&a_d[gr], pd);
    }
  }
}

// ---------------------------------------------------------------------------
// Layer-2 aggregate: H=1, C=128. Half-wave per edge, float4 loads.
// ---------------------------------------------------------------------------
__global__ __launch_bounds__(256) void agg2_kernel(
    const float* __restrict__ xw, const float* __restrict__ a_src,
    const float* __restrict__ a_dst, const int* __restrict__ indptr,
    const int* __restrict__ srcs, const float* __restrict__ bias,
    float* __restrict__ out) {
  int lane = threadIdx.x & 63;
  int n = blockIdx.x * 4 + (threadIdx.x >> 6);
  if (n >= N_NODES) return;
  int beg = indptr[n], end = indptr[n + 1];
  int deg = end - beg;
  float adn = a_dst[n];
  int half = lane >> 5, l32 = lane & 31;
  float4 acc = make_float4(0.f, 0.f, 0.f, 0.f);

  auto pairs = [&](int s, float al, int jn) {
    int jj = 0;
    for (; jj + 2 <= jn; jj += 2) {
      int sa = readlane_i(s, jj), sb = readlane_i(s, jj + 1);
      float aa = readlane_f(al, jj), ab = readlane_f(al, jj + 1);
      int sh = half ? sb : sa;
      float ah = half ? ab : aa;
      float4 v = *(const float4*)&xw[(size_t)sh * HID + l32 * 4];
      acc.x += ah * v.x; acc.y += ah * v.y; acc.z += ah * v.z; acc.w += ah * v.w;
    }
    if (jj < jn) {
      int sa = readlane_i(s, jj);
      float ah = half ? 0.f : readlane_f(al, jj);
      float4 v = *(const float4*)&xw[(size_t)sa * HID + l32 * 4];
      acc.x += ah * v.x; acc.y += ah * v.y; acc.z += ah * v.z; acc.w += ah * v.w;
    }
  };

  if (deg <= 64) {
    int j = beg + lane;
    int s = 0;
    float e = -INFINITY;
    if (j < end) { s = srcs[j]; e = leaky(a_src[s] + adn); }
    float m = e;
    for (int off = 1; off < 64; off <<= 1) m = fmaxf(m, __shfl_xor(m, off));
    float x = (j < end) ? expf(e - m) : 0.f;
    float d = x;
    for (int off = 1; off < 64; off <<= 1) d += __shfl_xor(d, off);
    float al = x / (d + 1e-16f);
    pairs(s, al, deg);
  } else {
    float m = -INFINITY;
    for (int j0 = beg; j0 < end; j0 += 64) {
      int j = j0 + lane;
      if (j < end) m = fmaxf(m, leaky(a_src[srcs[j]] + adn));
    }
    for (int off = 1; off < 64; off <<= 1) m = fmaxf(m, __shfl_xor(m, off));
    float d = 0.f;
    for (int j0 = beg; j0 < end; j0 += 64) {
      int j = j0 + lane;
      if (j < end) d += expf(leaky(a_src[srcs[j]] + adn) - m);
    }
    for (int off = 1; off < 64; off <<= 1) d += __shfl_xor(d, off);
    float rd = 1.f / (d + 1e-16f);
    for (int j0 = beg; j0 < end; j0 += 64) {
      int jn = min(64, end - j0);
      int j = j0 + lane;
      int s = 0;
      float al = 0.f;
      if (j < end) {
        s = srcs[j];
        al = expf(leaky(a_src[s] + adn) - m) * rd;
      }
      pairs(s, al, jn);
    }
  }

  acc.x += __shfl_xor(acc.x, 32); acc.y += __shfl_xor(acc.y, 32);
  acc.z += __shfl_xor(acc.z, 32); acc.w += __shfl_xor(acc.w, 32);
  if (half == 0) {
    float4 b = *(const float4*)&bias[l32 * 4];
    float4 o;
    o.x = elu(acc.x + b.x); o.y = elu(acc.y + b.y);
    o.z = elu(acc.z + b.z); o.w = elu(acc.w + b.w);
    *(float4*)&out[(size_t)n * HID + l32 * 4] = o;
  }
}

// ---------------------------------------------------------------------------
// Graph ranges (batch sorted), max-pool per graph, classifier head.
// ---------------------------------------------------------------------------
__global__ void gstart_kernel(const int* __restrict__ batch,
                              int* __restrict__ gstarts, int N, int G) {
  int t = threadIdx.x;
  if (t > G) return;
  int lo = 0, hi = N;
  while (lo < hi) {
    int mid = (lo + hi) >> 1;
    if (batch[mid] < t) lo = mid + 1; else hi = mid;
  }
  gstarts[t] = lo;
}

__global__ __launch_bounds__(HID) void pool_kernel(const float* __restrict__ out2,
                                                   const int* __restrict__ gstarts,
                                                   float* __restrict__ pooled) {
  int g = blockIdx.x, t = threadIdx.x;
  int beg = gstarts[g], end = gstarts[g + 1];
  float m = -INFINITY;
  for (int n = beg; n < end; ++n) m = fmaxf(m, out2[n * HID + t]);
  pooled[g * HID + t] = m;
}

__global__ __launch_bounds__(HID) void cls_kernel(const float* __restrict__ pooled,
                                                  const float* __restrict__ w1,
                                                  const float* __restrict__ b1,
                                                  const float* __restrict__ w2,
                                                  const float* __restrict__ b2,
                                                  float* __restrict__ out) {
  int g = blockIdx.x, t = threadIdx.x;
  __shared__ float sp[HID], sh1[HID / 2];
  sp[t] = pooled[g * HID + t];
  __syncthreads();
  if (t < HID / 2) {
    float s = b1[t];
    for (int k = 0; k < HID; ++k) s += sp[k] * w1[k * (HID / 2) + t];
    sh1[t] = fmaxf(s, 0.f);
  }
  __syncthreads();
  if (t < 2) {
    float o = b2[t];
    for (int k = 0; k < HID / 2; ++k) o += sh1[k] * w2[k * 2 + t];
    out[g * 2 + t] = o;
  }
}

// ---------------------------------------------------------------------------
extern "C" void kernel_launch(void* const* d_in, const int* in_sizes, int n_in,
                              void* d_out, int out_size, void* d_ws, size_t ws_size,
                              hipStream_t stream) {
  const float* x_scalar = (const float*)d_in[0];
  const int* x_opcode   = (const int*)d_in[1];
  const int* x_source   = (const int*)d_in[2];
  const int* x_sink     = (const int*)d_in[3];
  const int* x_string   = (const int*)d_in[4];
  const int* x_payload  = (const int*)d_in[5];
  const int* edge_index = (const int*)d_in[6];
  const int* batch      = (const int*)d_in[7];
  const float* emb_opcode = (const float*)d_in[8];
  const float* emb_source = (const float*)d_in[9];
  const float* emb_sink   = (const float*)d_in[10];
  const float* emb_string = (const float*)d_in[11];
  const float* emb_payload= (const float*)d_in[12];
  const float* ln_gamma = (const float*)d_in[13];
  const float* ln_beta  = (const float*)d_in[14];
  const float* W1       = (const float*)d_in[15];
  const float* att_src1 = (const float*)d_in[16];
  const float* att_dst1 = (const float*)d_in[17];
  const float* b1       = (const float*)d_in[18];
  const float* W2       = (const float*)d_in[19];
  const float* att_src2 = (const float*)d_in[20];
  const float* att_dst2 = (const float*)d_in[21];
  const float* b2       = (const float*)d_in[22];
  const float* cls_w1   = (const float*)d_in[23];
  const float* cls_b1   = (const float*)d_in[24];
  const float* cls_w2   = (const float*)d_in[25];
  const float* cls_b2   = (const float*)d_in[26];

  // Adaptive chunk: run layer-1 agg + head-GEMM in 1 pass if workspace allows.
  auto total_bytes = [&](int chunk) -> size_t {
    size_t f = (size_t)N_NODES * IN_DIM + (size_t)chunk * 4 * IN_DIM +
               (size_t)N_NODES * 512 + (size_t)N_NODES * HID +
               N_NODES * 4 * 2 + N_NODES * 2 + IN_DIM * 4 * 2 + N_GRAPHS * HID;
    size_t ii = (N_NODES + 1) + N_NODES * 2 + TOT_EDGES + (N_GRAPHS + 1);
    return f * 4 + ii * 4 + 256;
  };
  int chunk = (ws_size >= total_bytes(N_NODES)) ? N_NODES : CHUNK_SMALL;

  float* h      = (float*)d_ws;                        // [N,176]
  float* aggh   = h + (size_t)N_NODES * IN_DIM;        // [chunk*704]
  float* out1   = aggh + (size_t)chunk * 4 * IN_DIM;   // [N,512]
  float* out2   = out1 + (size_t)N_NODES * 512;        // [N,128]
  float* a1s    = out2 + (size_t)N_NODES * HID;        // [N,4]
  float* a1d    = a1s + N_NODES * 4;
  float* was4   = a1d + N_NODES * 4;                   // [176*4]
  float* wad4   = was4 + IN_DIM * 4;                   // [176*4]
  float* pooled = wad4 + IN_DIM * 4;                   // [G,128]
  int* indptr = (int*)(pooled + N_GRAPHS * HID);       // [N+1]
  int* cnt    = indptr + (N_NODES + 1);                // [N]   (zeroed)
  int* cursor = cnt + N_NODES;                         // [N]   (zeroed)
  float* a2s  = (float*)(cursor + N_NODES);            // [N]   (zeroed)
  float* a2d  = a2s + N_NODES;                         // [N]   (zeroed)
  int* srcs   = (int*)(a2d + N_NODES);                 // [E+N]
  int* gstarts= srcs + TOT_EDGES;                      // [G+1]
  float* xw2  = h;  // alias: h dead after last agg1h; xw2 [N,128] fits in h [N,176]

  // zero cnt, cursor, a2s, a2d in one shot (contiguous)
  hipMemsetAsync(cnt, 0, 4 * N_NODES * sizeof(int), stream);

  feats_ln_kernel<<<N_NODES, 192, 0, stream>>>(
      x_scalar, x_opcode, x_source, x_sink, x_string, x_payload,
      emb_opcode, emb_source, emb_sink, emb_string, emb_payload,
      ln_gamma, ln_beta, h);

  int nthreads = TOT_EDGES;
  count_kernel<<<(nthreads + 255) / 256, 256, 0, stream>>>(edge_index, cnt, N_EDGES, N_NODES);
  prefix_kernel<<<1, 256, 0, stream>>>(cnt, indptr, N_NODES, TOT_EDGES);
  scatter_kernel<<<(nthreads + 255) / 256, 256, 0, stream>>>(edge_index, indptr, cursor, srcs, N_EDGES, N_NODES);

  wasd_kernel<<<(IN_DIM + 3) / 4, 256, 0, stream>>>(W1, att_src1, att_dst1, was4, wad4);

  const int NB4 = (N_NODES + 3) / 4;
  att1h_kernel<<<NB4, 256, 0, stream>>>(h, was4, wad4, a1s, a1d);

  for (int n0 = 0; n0 < N_NODES; n0 += chunk) {
    int nM = min(chunk, N_NODES - n0);
    agg1h_kernel<<<(nM + 3) / 4, 256, 0, stream>>>(h, a1s, a1d, indptr, srcs, aggh, n0, nM);
    gemm_head_kernel<<<dim3(2, (nM + 63) / 64, 4), 256, 0, stream>>>(
        aggh, W1, b1, out1, nM, n0);
  }

  // GEMM2 + fused att2 logits: xw2 = out1@W2, a2s/a2d accumulated per row.
  gemm2att_kernel<<<dim3(2, (N_NODES + 63) / 64), 256, 0, stream>>>(
      out1, W2, att_src2, att_dst2, xw2, a2s, a2d, N_NODES);

  agg2_kernel<<<NB4, 256, 0, stream>>>(xw2, a2s, a2d, indptr, srcs, b2, out2);

  gstart_kernel<<<1, 128, 0, stream>>>(batch, gstarts, N_NODES, N_GRAPHS);
  pool_kernel<<<N_GRAPHS, HID, 0, stream>>>(out2, gstarts, pooled);
  cls_kernel<<<N_GRAPHS, HID, 0, stream>>>(pooled, cls_w1, cls_b1, cls_w2, cls_b2, (float*)d_out);
}

// Round 10
// 458.068 us; speedup vs baseline: 1.0833x; 1.0833x over previous
//
#include <hip/hip_runtime.h>
#include <hip/hip_bf16.h>
#include <math.h>

// Problem constants (match reference setup_inputs()).
#define N_NODES 20000
#define N_EDGES 320000
#define N_GRAPHS 64
#define SEQ 20
#define SCALAR 16
#define EMB 32
#define HID 128
#define IN_DIM 176         // SCALAR + 5*EMB
#define TOT_EDGES (N_EDGES + N_NODES)  // with self loops
#define CHUNK_SMALL 10000  // fallback node chunk when workspace is tight

__device__ inline float readlane_f(float v, int l) {
  return __uint_as_float(__builtin_amdgcn_readlane(__float_as_uint(v), l));
}
__device__ inline int readlane_i(int v, int l) {
  return __builtin_amdgcn_readlane(v, l);
}
__device__ inline float leaky(float e) { return e >= 0.f ? e : 0.2f * e; }
__device__ inline float elu(float v) { return v > 0.f ? v : expf(v) - 1.f; }

// ---------------------------------------------------------------------------
// feats+LN, wave-per-node (4 nodes / 256-thread block, ZERO barriers).
// Lane owns dims {lane, 64+lane, 128+lane(<48)}. Indices staged per-wave in
// LDS (same wave writes+reads -> wave-synchronous, no __syncthreads).
// ---------------------------------------------------------------------------
__global__ __launch_bounds__(256) void feats_ln_kernel(
    const float* __restrict__ xs,
    const int* __restrict__ i0, const int* __restrict__ i1,
    const int* __restrict__ i2, const int* __restrict__ i3,
    const int* __restrict__ i4,
    const float* __restrict__ t0, const float* __restrict__ t1,
    const float* __restrict__ t2, const float* __restrict__ t3,
    const float* __restrict__ t4,
    const float* __restrict__ gamma, const float* __restrict__ beta,
    float* __restrict__ hout) {
  int lane = threadIdx.x & 63;
  int w = threadIdx.x >> 6;
  int n = blockIdx.x * 4 + w;
  if (n >= N_NODES) return;
  __shared__ int sidx[4][100];
  {
    int j = lane;                       // 0..63 -> tabs 0..3
    int tab = j / 20, l = j - tab * 20;
    const int* ip = tab == 0 ? i0 : tab == 1 ? i1 : tab == 2 ? i2 : i3;
    sidx[w][j] = ip[n * SEQ + l];
    if (lane < 36) {
      int j2 = 64 + lane;               // 64..99 -> tabs 3,4
      int tab2 = j2 / 20, l2 = j2 - tab2 * 20;
      const int* ip2 = tab2 == 3 ? i3 : i4;
      sidx[w][j2] = ip2[n * SEQ + l2];
    }
  }
  bool l48 = lane < 48;
  float f0, f1, f2 = 0.f;
  if (lane < SCALAR) {
    f0 = xs[n * SCALAR + lane];
  } else {
    int tt = lane - SCALAR, tab = tt >> 5, d = tt & 31;  // tab 0 or 1
    const float* tp = tab == 0 ? t0 : t1;
    float sum = 0.f, cnt = 0.f;
#pragma unroll
    for (int l = 0; l < SEQ; ++l) {
      int id = sidx[w][tab * 20 + l];
      if (id != 0) { sum += tp[id * EMB + d]; cnt += 1.f; }
    }
    f0 = sum / (cnt + 1e-9f);
  }
  {
    int tt = 48 + lane, tab = tt >> 5, d = tt & 31;      // tab 1,2,3
    const float* tp = tab == 1 ? t1 : tab == 2 ? t2 : t3;
    float sum = 0.f, cnt = 0.f;
#pragma unroll
    for (int l = 0; l < SEQ; ++l) {
      int id = sidx[w][tab * 20 + l];
      if (id != 0) { sum += tp[id * EMB + d]; cnt += 1.f; }
    }
    f1 = sum / (cnt + 1e-9f);
  }
  if (l48) {
    int tt = 112 + lane, tab = tt >> 5, d = tt & 31;     // tab 3 or 4
    const float* tp = tab == 3 ? t3 : t4;
    float sum = 0.f, cnt = 0.f;
#pragma unroll
    for (int l = 0; l < SEQ; ++l) {
      int id = sidx[w][tab * 20 + l];
      if (id != 0) { sum += tp[id * EMB + d]; cnt += 1.f; }
    }
    f2 = sum / (cnt + 1e-9f);
  }
  float s = f0 + f1 + f2;  // f2==0 for lane>=48
  for (int off = 1; off < 64; off <<= 1) s += __shfl_xor(s, off);
  float mu = s / (float)IN_DIM;
  float v = (f0 - mu) * (f0 - mu) + (f1 - mu) * (f1 - mu) +
            (l48 ? (f2 - mu) * (f2 - mu) : 0.f);
  for (int off = 1; off < 64; off <<= 1) v += __shfl_xor(v, off);
  float rstd = 1.0f / sqrtf(v / (float)IN_DIM + 1e-5f);
  float* hr = hout + (size_t)n * IN_DIM;
  hr[lane] = (f0 - mu) * rstd * gamma[lane] + beta[lane];
  hr[64 + lane] = (f1 - mu) * rstd * gamma[64 + lane] + beta[64 + lane];
  if (l48) hr[128 + lane] = (f2 - mu) * rstd * gamma[128 + lane] + beta[128 + lane];
}

// ---------------------------------------------------------------------------
// CSR build.
// ---------------------------------------------------------------------------
__global__ void count_kernel(const int* __restrict__ edge_index,
                             int* __restrict__ cnt, int E, int N) {
  int i = blockIdx.x * blockDim.x + threadIdx.x;
  if (i < E) {
    atomicAdd(&cnt[edge_index[E + i]], 1);
  } else if (i < E + N) {
    atomicAdd(&cnt[i - E], 1);  // self loop dst = node
  }
}

__global__ __launch_bounds__(256) void prefix_kernel(const int* __restrict__ cnt,
                                                     int* __restrict__ indptr,
                                                     int n, int total) {
  __shared__ int ssum[256];
  int t = threadIdx.x;
  int per = (n + 255) / 256;
  int beg = t * per, end = min(beg + per, n);
  int s = 0;
  for (int i = beg; i < end; ++i) s += cnt[i];
  ssum[t] = s;
  __syncthreads();
  if (t == 0) {
    int run = 0;
    for (int i = 0; i < 256; ++i) { int v = ssum[i]; ssum[i] = run; run += v; }
  }
  __syncthreads();
  int run = ssum[t];
  for (int i = beg; i < end; ++i) { indptr[i] = run; run += cnt[i]; }
  if (t == 0) indptr[n] = total;
}

__global__ void scatter_kernel(const int* __restrict__ edge_index,
                               const int* __restrict__ indptr,
                               int* __restrict__ cursor,
                               int* __restrict__ srcs, int E, int N) {
  int i = blockIdx.x * blockDim.x + threadIdx.x;
  int s, d;
  if (i < E) { s = edge_index[i]; d = edge_index[E + i]; }
  else if (i < E + N) { s = i - E; d = s; }
  else return;
  int pos = indptr[d] + atomicAdd(&cursor[d], 1);
  srcs[pos] = s;
}

// ---------------------------------------------------------------------------
// was/wad precompute, wave-per-k: was[k][h] = sum_c W1[k,h*128+c]*att_s[h*128+c].
// ---------------------------------------------------------------------------
__global__ __launch_bounds__(256) void wasd_kernel(
    const float* __restrict__ W1, const float* __restrict__ att_s,
    const float* __restrict__ att_d, float* __restrict__ was4,
    float* __restrict__ wad4) {
  int lane = threadIdx.x & 63;
  int k = blockIdx.x * 4 + (threadIdx.x >> 6);
  if (k >= IN_DIM) return;
  const float* wrow = W1 + (size_t)k * 512;
  float s[4], d[4];
#pragma unroll
  for (int hh = 0; hh < 4; ++hh) {
    float w0 = wrow[hh * 128 + lane], w1 = wrow[hh * 128 + 64 + lane];
    float a0 = att_s[hh * 128 + lane], a1 = att_s[hh * 128 + 64 + lane];
    float c0 = att_d[hh * 128 + lane], c1 = att_d[hh * 128 + 64 + lane];
    s[hh] = w0 * a0 + w1 * a1;
    d[hh] = w0 * c0 + w1 * c1;
  }
  for (int off = 1; off < 64; off <<= 1) {
#pragma unroll
    for (int hh = 0; hh < 4; ++hh) {
      s[hh] += __shfl_xor(s[hh], off);
      d[hh] += __shfl_xor(d[hh], off);
    }
  }
  if (lane == 0) {
    *(float4*)&was4[k * 4] = make_float4(s[0], s[1], s[2], s[3]);
    *(float4*)&wad4[k * 4] = make_float4(d[0], d[1], d[2], d[3]);
  }
}

// ---------------------------------------------------------------------------
// Attention logits layer 1 from h. Wave-per-node (4 nodes / block).
// ---------------------------------------------------------------------------
__global__ __launch_bounds__(256) void att1h_kernel(
    const float* __restrict__ h, const float* __restrict__ was4,
    const float* __restrict__ wad4, float* __restrict__ a_s,
    float* __restrict__ a_d) {
  int lane = threadIdx.x & 63;
  int n = blockIdx.x * 4 + (threadIdx.x >> 6);
  if (n >= N_NODES) return;
  const float* hr = h + (size_t)n * IN_DIM;
  bool l48 = lane < 48;
  float v0 = hr[lane];
  float v1 = hr[64 + lane];
  float v2 = l48 ? hr[128 + lane] : 0.f;
  const float4* wsv = (const float4*)was4;
  const float4* wdv = (const float4*)wad4;
  float4 wsa = wsv[lane], wsb = wsv[64 + lane];
  float4 wsc = l48 ? wsv[128 + lane] : make_float4(0.f, 0.f, 0.f, 0.f);
  float4 wda = wdv[lane], wdb = wdv[64 + lane];
  float4 wdc = l48 ? wdv[128 + lane] : make_float4(0.f, 0.f, 0.f, 0.f);
  float ps0 = v0 * wsa.x + v1 * wsb.x + v2 * wsc.x;
  float ps1 = v0 * wsa.y + v1 * wsb.y + v2 * wsc.y;
  float ps2 = v0 * wsa.z + v1 * wsb.z + v2 * wsc.z;
  float ps3 = v0 * wsa.w + v1 * wsb.w + v2 * wsc.w;
  float pd0 = v0 * wda.x + v1 * wdb.x + v2 * wdc.x;
  float pd1 = v0 * wda.y + v1 * wdb.y + v2 * wdc.y;
  float pd2 = v0 * wda.z + v1 * wdb.z + v2 * wdc.z;
  float pd3 = v0 * wda.w + v1 * wdb.w + v2 * wdc.w;
  for (int off = 1; off < 64; off <<= 1) {
    ps0 += __shfl_xor(ps0, off); ps1 += __shfl_xor(ps1, off);
    ps2 += __shfl_xor(ps2, off); ps3 += __shfl_xor(ps3, off);
    pd0 += __shfl_xor(pd0, off); pd1 += __shfl_xor(pd1, off);
    pd2 += __shfl_xor(pd2, off); pd3 += __shfl_xor(pd3, off);
  }
  if (lane == 0) {
    *(float4*)&a_s[n * 4] = make_float4(ps0, ps1, ps2, ps3);
    *(float4*)&a_d[n * 4] = make_float4(pd0, pd1, pd2, pd3);
  }
}

// ---------------------------------------------------------------------------
// Layer-1 softmax + aggregate h (176-dim) per head -> aggh[(ln*4+h)*176+k].
// Wave-per-node, zero barriers. Nodes [n0, n0+nM).
// ---------------------------------------------------------------------------
__global__ __launch_bounds__(256) void agg1h_kernel(
    const float* __restrict__ h, const float* __restrict__ a_src,
    const float* __restrict__ a_dst, const int* __restrict__ indptr,
    const int* __restrict__ srcs, float* __restrict__ aggh,
    int n0, int nM) {
  int lane = threadIdx.x & 63;
  int ln = blockIdx.x * 4 + (threadIdx.x >> 6);
  if (ln >= nM) return;
  int n = n0 + ln;
  int beg = indptr[n], end = indptr[n + 1];
  int deg = end - beg;
  float4 ad = *(const float4*)&a_dst[n * 4];
  bool l48 = lane < 48;
  float acc[4][3] = {};

  auto body = [&](int s, float al0, float al1, float al2, float al3) {
    const float* r = h + (size_t)s * IN_DIM;
    float v0 = r[lane];
    float v1 = r[64 + lane];
    float v2 = l48 ? r[128 + lane] : 0.f;
    acc[0][0] += al0 * v0; acc[0][1] += al0 * v1; acc[0][2] += al0 * v2;
    acc[1][0] += al1 * v0; acc[1][1] += al1 * v1; acc[1][2] += al1 * v2;
    acc[2][0] += al2 * v0; acc[2][1] += al2 * v1; acc[2][2] += al2 * v2;
    acc[3][0] += al3 * v0; acc[3][1] += al3 * v1; acc[3][2] += al3 * v2;
  };

  if (deg <= 64) {
    int j = beg + lane;
    int s = 0;
    float e0 = -INFINITY, e1 = -INFINITY, e2 = -INFINITY, e3 = -INFINITY;
    if (j < end) {
      s = srcs[j];
      float4 as = *(const float4*)&a_src[s * 4];
      e0 = leaky(as.x + ad.x); e1 = leaky(as.y + ad.y);
      e2 = leaky(as.z + ad.z); e3 = leaky(as.w + ad.w);
    }
    float m0 = e0, m1 = e1, m2 = e2, m3 = e3;
    for (int off = 1; off < 64; off <<= 1) {
      m0 = fmaxf(m0, __shfl_xor(m0, off)); m1 = fmaxf(m1, __shfl_xor(m1, off));
      m2 = fmaxf(m2, __shfl_xor(m2, off)); m3 = fmaxf(m3, __shfl_xor(m3, off));
    }
    float x0 = (j < end) ? expf(e0 - m0) : 0.f;
    float x1 = (j < end) ? expf(e1 - m1) : 0.f;
    float x2 = (j < end) ? expf(e2 - m2) : 0.f;
    float x3 = (j < end) ? expf(e3 - m3) : 0.f;
    float d0 = x0, d1 = x1, d2 = x2, d3 = x3;
    for (int off = 1; off < 64; off <<= 1) {
      d0 += __shfl_xor(d0, off); d1 += __shfl_xor(d1, off);
      d2 += __shfl_xor(d2, off); d3 += __shfl_xor(d3, off);
    }
    float al0 = x0 / (d0 + 1e-16f), al1 = x1 / (d1 + 1e-16f);
    float al2 = x2 / (d2 + 1e-16f), al3 = x3 / (d3 + 1e-16f);
    int jj = 0;
    for (; jj + 2 <= deg; jj += 2) {
      int sa = readlane_i(s, jj), sb = readlane_i(s, jj + 1);
      float a0 = readlane_f(al0, jj), a1 = readlane_f(al1, jj);
      float a2 = readlane_f(al2, jj), a3 = readlane_f(al3, jj);
      float b0 = readlane_f(al0, jj + 1), b1 = readlane_f(al1, jj + 1);
      float b2 = readlane_f(al2, jj + 1), b3 = readlane_f(al3, jj + 1);
      body(sa, a0, a1, a2, a3);
      body(sb, b0, b1, b2, b3);
    }
    if (jj < deg) {
      int sa = readlane_i(s, jj);
      body(sa, readlane_f(al0, jj), readlane_f(al1, jj),
           readlane_f(al2, jj), readlane_f(al3, jj));
    }
  } else {
    float m0 = -INFINITY, m1 = -INFINITY, m2 = -INFINITY, m3 = -INFINITY;
    for (int j0 = beg; j0 < end; j0 += 64) {
      int j = j0 + lane;
      if (j < end) {
        int s = srcs[j];
        float4 as = *(const float4*)&a_src[s * 4];
        m0 = fmaxf(m0, leaky(as.x + ad.x)); m1 = fmaxf(m1, leaky(as.y + ad.y));
        m2 = fmaxf(m2, leaky(as.z + ad.z)); m3 = fmaxf(m3, leaky(as.w + ad.w));
      }
    }
    for (int off = 1; off < 64; off <<= 1) {
      m0 = fmaxf(m0, __shfl_xor(m0, off)); m1 = fmaxf(m1, __shfl_xor(m1, off));
      m2 = fmaxf(m2, __shfl_xor(m2, off)); m3 = fmaxf(m3, __shfl_xor(m3, off));
    }
    float d0 = 0.f, d1 = 0.f, d2 = 0.f, d3 = 0.f;
    for (int j0 = beg; j0 < end; j0 += 64) {
      int j = j0 + lane;
      if (j < end) {
        int s = srcs[j];
        float4 as = *(const float4*)&a_src[s * 4];
        d0 += expf(leaky(as.x + ad.x) - m0); d1 += expf(leaky(as.y + ad.y) - m1);
        d2 += expf(leaky(as.z + ad.z) - m2); d3 += expf(leaky(as.w + ad.w) - m3);
      }
    }
    for (int off = 1; off < 64; off <<= 1) {
      d0 += __shfl_xor(d0, off); d1 += __shfl_xor(d1, off);
      d2 += __shfl_xor(d2, off); d3 += __shfl_xor(d3, off);
    }
    float r0 = 1.f / (d0 + 1e-16f), r1 = 1.f / (d1 + 1e-16f);
    float r2 = 1.f / (d2 + 1e-16f), r3 = 1.f / (d3 + 1e-16f);
    for (int j0 = beg; j0 < end; j0 += 64) {
      int jn = min(64, end - j0);
      int j = j0 + lane;
      int s = 0;
      float al0 = 0.f, al1 = 0.f, al2 = 0.f, al3 = 0.f;
      if (j < end) {
        s = srcs[j];
        float4 as = *(const float4*)&a_src[s * 4];
        al0 = expf(leaky(as.x + ad.x) - m0) * r0;
        al1 = expf(leaky(as.y + ad.y) - m1) * r1;
        al2 = expf(leaky(as.z + ad.z) - m2) * r2;
        al3 = expf(leaky(as.w + ad.w) - m3) * r3;
      }
      for (int jj = 0; jj < jn; ++jj) {
        body(readlane_i(s, jj), readlane_f(al0, jj), readlane_f(al1, jj),
             readlane_f(al2, jj), readlane_f(al3, jj));
      }
    }
  }

  size_t base = (size_t)ln * (4 * IN_DIM);
#pragma unroll
  for (int hh = 0; hh < 4; ++hh) {
    aggh[base + hh * IN_DIM + lane] = acc[hh][0];
    aggh[base + hh * IN_DIM + 64 + lane] = acc[hh][1];
    if (l48) aggh[base + hh * IN_DIM + 128 + lane] = acc[hh][2];
  }
}

// ---------------------------------------------------------------------------
// Head-GEMM v4: BM=64, BN=128 (full head), BK=16, TM=4, TN=8.
// A-tile read once per row block (halves aggh re-fetch vs BN=64 split).
// Cols split as {tc*4+j} and {64+tc*4+j} -> both 2-way LDS reads (free).
// grid (ceil(M/64), 1, 4 heads) = 1252 blocks.
// ---------------------------------------------------------------------------
__global__ __launch_bounds__(256) void gemm_head_kernel(
    const float* __restrict__ aggh, const float* __restrict__ W1,
    const float* __restrict__ b1, float* __restrict__ out1,
    int M, int n0) {
  const int BM = 64, BK = 16;
  __shared__ float As[BK][BM + 4];
  __shared__ float Bs[BK][128 + 4];
  int tid = threadIdx.x;
  int hh = blockIdx.z;
  int tr = tid >> 4, tc = tid & 15;
  int row0 = blockIdx.x * BM;
  float acc[4][8] = {};
  for (int k0 = 0; k0 < IN_DIM; k0 += BK) {
    {
      int r = tid >> 2, kq = (tid & 3) * 4;  // 256 float4 = BM*BK/4
      int gr = row0 + r;
      float4 v = make_float4(0.f, 0.f, 0.f, 0.f);
      if (gr < M) v = *(const float4*)&aggh[((size_t)gr * 4 + hh) * IN_DIM + k0 + kq];
      As[kq + 0][r] = v.x; As[kq + 1][r] = v.y;
      As[kq + 2][r] = v.z; As[kq + 3][r] = v.w;
    }
#pragma unroll
    for (int it = 0; it < 2; ++it) {       // 512 float4 = BK*128/4
      int i = tid + it * 256;
      int kk = i >> 5, cq = (i & 31) * 4;
      *(float4*)&Bs[kk][cq] =
          *(const float4*)&W1[(size_t)(k0 + kk) * 512 + hh * 128 + cq];
    }
    __syncthreads();
#pragma unroll
    for (int kk = 0; kk < BK; ++kk) {
      float a[4], b[8];
      *(float4*)&a[0] = *(const float4*)&As[kk][tr * 4];
      *(float4*)&b[0] = *(const float4*)&Bs[kk][tc * 4];
      *(float4*)&b[4] = *(const float4*)&Bs[kk][64 + tc * 4];
#pragma unroll
      for (int i = 0; i < 4; ++i)
#pragma unroll
        for (int j = 0; j < 8; ++j) acc[i][j] += a[i] * b[j];
    }
    __syncthreads();
  }
  float4 bv0 = *(const float4*)&b1[hh * 128 + tc * 4];
  float4 bv1 = *(const float4*)&b1[hh * 128 + 64 + tc * 4];
#pragma unroll
  for (int i = 0; i < 4; ++i) {
    int gr = row0 + tr * 4 + i;
    if (gr >= M) continue;
    float* drow = &out1[(size_t)(n0 + gr) * 512 + hh * 128];
    float4 o0, o1;
    o0.x = elu(acc[i][0] + bv0.x); o0.y = elu(acc[i][1] + bv0.y);
    o0.z = elu(acc[i][2] + bv0.z); o0.w = elu(acc[i][3] + bv0.w);
    o1.x = elu(acc[i][4] + bv1.x); o1.y = elu(acc[i][5] + bv1.y);
    o1.z = elu(acc[i][6] + bv1.z); o1.w = elu(acc[i][7] + bv1.w);
    *(float4*)&drow[tc * 4] = o0;
    *(float4*)&drow[64 + tc * 4] = o1;
  }
}

// ---------------------------------------------------------------------------
// GEMM2 + fused layer-2 att logits: xw2 = out1@W2; a2s/a2d partial dots via
// 16-lane shfl reduce + one atomicAdd per row-half (a2s/a2d pre-zeroed).
// BM=64, BN=64, BK=16, TM=4, TN=4. grid (2, ceil(M/64)) = 626 blocks.
// ---------------------------------------------------------------------------
__global__ __launch_bounds__(256) void gemm2att_kernel(
    const float* __restrict__ A, const float* __restrict__ W2,
    const float* __restrict__ att_s, const float* __restrict__ att_d,
    float* __restrict__ C, float* __restrict__ a_s, float* __restrict__ a_d,
    int M) {
  const int BM = 64, BN = 64, BK = 16;
  __shared__ float As[BK][BM + 4];
  __shared__ float Bs[BK][BN + 4];
  int tid = threadIdx.x;
  int tr = tid >> 4, tc = tid & 15;
  int row0 = blockIdx.y * BM, col0 = blockIdx.x * BN;
  float acc[4][4] = {};
  for (int k0 = 0; k0 < 512; k0 += BK) {
    {
      int r = tid >> 2, kq = (tid & 3) * 4;  // 256 float4 = BM*BK/4
      int gr = row0 + r;
      float4 v = make_float4(0.f, 0.f, 0.f, 0.f);
      if (gr < M) v = *(const float4*)&A[(size_t)gr * 512 + k0 + kq];
      As[kq + 0][r] = v.x; As[kq + 1][r] = v.y;
      As[kq + 2][r] = v.z; As[kq + 3][r] = v.w;
    }
    {
      int kk = tid >> 4, cq = (tid & 15) * 4;  // 256 float4 = BK*BN/4
      *(float4*)&Bs[kk][cq] = *(const float4*)&W2[(size_t)(k0 + kk) * 128 + col0 + cq];
    }
    __syncthreads();
#pragma unroll
    for (int kk = 0; kk < BK; ++kk) {
      float a[4], b[4];
      *(float4*)&a[0] = *(const float4*)&As[kk][tr * 4];
      *(float4*)&b[0] = *(const float4*)&Bs[kk][tc * 4];
#pragma unroll
      for (int i = 0; i < 4; ++i)
#pragma unroll
        for (int j = 0; j < 4; ++j) acc[i][j] += a[i] * b[j];
    }
    __syncthreads();
  }
  float4 asv = *(const float4*)&att_s[col0 + tc * 4];
  float4 adv = *(const float4*)&att_d[col0 + tc * 4];
#pragma unroll
  for (int i = 0; i < 4; ++i) {
    int gr = row0 + tr * 4 + i;
    if (gr >= M) continue;  // uniform across the 16 tc lanes
    *(float4*)&C[(size_t)gr * 128 + col0 + tc * 4] = *(float4*)&acc[i][0];
    float ps = acc[i][0] * asv.x + acc[i][1] * asv.y +
               acc[i][2] * asv.z + acc[i][3] * asv.w;
    float pd = acc[i][0] * adv.x + acc[i][1] * adv.y +
               acc[i][2] * adv.z + acc[i][3] * adv.w;
    for (int off = 1; off < 16; off <<= 1) {
      ps += __shfl_xor(ps, off);
      pd += __shfl_xor(pd, off);
    }
    if (tc == 0) {
      atomicAdd(&a_s[gr], ps);
      atomicAdd(&a_d[gr], pd);
    }
  }
}

// ---------------------------------------------------------------------------
// Layer-2 aggregate: H=1, C=128. Half-wave per edge, float4 loads.
// ---------------------------------------------------------------------------
__global__ __launch_bounds__(256) void agg2_kernel(
    const float* __restrict__ xw, const float* __restrict__ a_src,
    const float* __restrict__ a_dst, const int* __restrict__ indptr,
    const int* __restrict__ srcs, const float* __restrict__ bias,
    float* __restrict__ out) {
  int lane = threadIdx.x & 63;
  int n = blockIdx.x * 4 + (threadIdx.x >> 6);
  if (n >= N_NODES) return;
  int beg = indptr[n], end = indptr[n + 1];
  int deg = end - beg;
  float adn = a_dst[n];
  int half = lane >> 5, l32 = lane & 31;
  float4 acc = make_float4(0.f, 0.f, 0.f, 0.f);

  auto pairs = [&](int s, float al, int jn) {
    int jj = 0;
    for (; jj + 2 <= jn; jj += 2) {
      int sa = readlane_i(s, jj), sb = readlane_i(s, jj + 1);
      float aa = readlane_f(al, jj), ab = readlane_f(al, jj + 1);
      int sh = half ? sb : sa;
      float ah = half ? ab : aa;
      float4 v = *(const float4*)&xw[(size_t)sh * HID + l32 * 4];
      acc.x += ah * v.x; acc.y += ah * v.y; acc.z += ah * v.z; acc.w += ah * v.w;
    }
    if (jj < jn) {
      int sa = readlane_i(s, jj);
      float ah = half ? 0.f : readlane_f(al, jj);
      float4 v = *(const float4*)&xw[(size_t)sa * HID + l32 * 4];
      acc.x += ah * v.x; acc.y += ah * v.y; acc.z += ah * v.z; acc.w += ah * v.w;
    }
  };

  if (deg <= 64) {
    int j = beg + lane;
    int s = 0;
    float e = -INFINITY;
    if (j < end) { s = srcs[j]; e = leaky(a_src[s] + adn); }
    float m = e;
    for (int off = 1; off < 64; off <<= 1) m = fmaxf(m, __shfl_xor(m, off));
    float x = (j < end) ? expf(e - m) : 0.f;
    float d = x;
    for (int off = 1; off < 64; off <<= 1) d += __shfl_xor(d, off);
    float al = x / (d + 1e-16f);
    pairs(s, al, deg);
  } else {
    float m = -INFINITY;
    for (int j0 = beg; j0 < end; j0 += 64) {
      int j = j0 + lane;
      if (j < end) m = fmaxf(m, leaky(a_src[srcs[j]] + adn));
    }
    for (int off = 1; off < 64; off <<= 1) m = fmaxf(m, __shfl_xor(m, off));
    float d = 0.f;
    for (int j0 = beg; j0 < end; j0 += 64) {
      int j = j0 + lane;
      if (j < end) d += expf(leaky(a_src[srcs[j]] + adn) - m);
    }
    for (int off = 1; off < 64; off <<= 1) d += __shfl_xor(d, off);
    float rd = 1.f / (d + 1e-16f);
    for (int j0 = beg; j0 < end; j0 += 64) {
      int jn = min(64, end - j0);
      int j = j0 + lane;
      int s = 0;
      float al = 0.f;
      if (j < end) {
        s = srcs[j];
        al = expf(leaky(a_src[s] + adn) - m) * rd;
      }
      pairs(s, al, jn);
    }
  }

  acc.x += __shfl_xor(acc.x, 32); acc.y += __shfl_xor(acc.y, 32);
  acc.z += __shfl_xor(acc.z, 32); acc.w += __shfl_xor(acc.w, 32);
  if (half == 0) {
    float4 b = *(const float4*)&bias[l32 * 4];
    float4 o;
    o.x = elu(acc.x + b.x); o.y = elu(acc.y + b.y);
    o.z = elu(acc.z + b.z); o.w = elu(acc.w + b.w);
    *(float4*)&out[(size_t)n * HID + l32 * 4] = o;
  }
}

// ---------------------------------------------------------------------------
// Graph ranges (batch sorted), max-pool per graph, classifier head.
// ---------------------------------------------------------------------------
__global__ void gstart_kernel(const int* __restrict__ batch,
                              int* __restrict__ gstarts, int N, int G) {
  int t = threadIdx.x;
  if (t > G) return;
  int lo = 0, hi = N;
  while (lo < hi) {
    int mid = (lo + hi) >> 1;
    if (batch[mid] < t) lo = mid + 1; else hi = mid;
  }
  gstarts[t] = lo;
}

__global__ __launch_bounds__(HID) void pool_kernel(const float* __restrict__ out2,
                                                   const int* __restrict__ gstarts,
                                                   float* __restrict__ pooled) {
  int g = blockIdx.x, t = threadIdx.x;
  int beg = gstarts[g], end = gstarts[g + 1];
  float m = -INFINITY;
  for (int n = beg; n < end; ++n) m = fmaxf(m, out2[n * HID + t]);
  pooled[g * HID + t] = m;
}

__global__ __launch_bounds__(HID) void cls_kernel(const float* __restrict__ pooled,
                                                  const float* __restrict__ w1,
                                                  const float* __restrict__ b1,
                                                  const float* __restrict__ w2,
                                                  const float* __restrict__ b2,
                                                  float* __restrict__ out) {
  int g = blockIdx.x, t = threadIdx.x;
  __shared__ float sp[HID], sh1[HID / 2];
  sp[t] = pooled[g * HID + t];
  __syncthreads();
  if (t < HID / 2) {
    float s = b1[t];
    for (int k = 0; k < HID; ++k) s += sp[k] * w1[k * (HID / 2) + t];
    sh1[t] = fmaxf(s, 0.f);
  }
  __syncthreads();
  if (t < 2) {
    float o = b2[t];
    for (int k = 0; k < HID / 2; ++k) o += sh1[k] * w2[k * 2 + t];
    out[g * 2 + t] = o;
  }
}

// ---------------------------------------------------------------------------
extern "C" void kernel_launch(void* const* d_in, const int* in_sizes, int n_in,
                              void* d_out, int out_size, void* d_ws, size_t ws_size,
                              hipStream_t stream) {
  const float* x_scalar = (const float*)d_in[0];
  const int* x_opcode   = (const int*)d_in[1];
  const int* x_source   = (const int*)d_in[2];
  const int* x_sink     = (const int*)d_in[3];
  const int* x_string   = (const int*)d_in[4];
  const int* x_payload  = (const int*)d_in[5];
  const int* edge_index = (const int*)d_in[6];
  const int* batch      = (const int*)d_in[7];
  const float* emb_opcode = (const float*)d_in[8];
  const float* emb_source = (const float*)d_in[9];
  const float* emb_sink   = (const float*)d_in[10];
  const float* emb_string = (const float*)d_in[11];
  const float* emb_payload= (const float*)d_in[12];
  const float* ln_gamma = (const float*)d_in[13];
  const float* ln_beta  = (const float*)d_in[14];
  const float* W1       = (const float*)d_in[15];
  const float* att_src1 = (const float*)d_in[16];
  const float* att_dst1 = (const float*)d_in[17];
  const float* b1       = (const float*)d_in[18];
  const float* W2       = (const float*)d_in[19];
  const float* att_src2 = (const float*)d_in[20];
  const float* att_dst2 = (const float*)d_in[21];
  const float* b2       = (const float*)d_in[22];
  const float* cls_w1   = (const float*)d_in[23];
  const float* cls_b1   = (const float*)d_in[24];
  const float* cls_w2   = (const float*)d_in[25];
  const float* cls_b2   = (const float*)d_in[26];

  // Adaptive chunk: run layer-1 agg + head-GEMM in 1 pass if workspace allows.
  auto total_bytes = [&](int chunk) -> size_t {
    size_t f = (size_t)N_NODES * IN_DIM + (size_t)chunk * 4 * IN_DIM +
               (size_t)N_NODES * 512 + (size_t)N_NODES * HID +
               N_NODES * 4 * 2 + N_NODES * 2 + IN_DIM * 4 * 2 + N_GRAPHS * HID;
    size_t ii = (N_NODES + 1) + N_NODES * 2 + TOT_EDGES + (N_GRAPHS + 1);
    return f * 4 + ii * 4 + 256;
  };
  int chunk = (ws_size >= total_bytes(N_NODES)) ? N_NODES : CHUNK_SMALL;

  float* h      = (float*)d_ws;                        // [N,176]
  float* aggh   = h + (size_t)N_NODES * IN_DIM;        // [chunk*704]
  float* out1   = aggh + (size_t)chunk * 4 * IN_DIM;   // [N,512]
  float* out2   = out1 + (size_t)N_NODES * 512;        // [N,128]
  float* a1s    = out2 + (size_t)N_NODES * HID;        // [N,4]
  float* a1d    = a1s + N_NODES * 4;
  float* was4   = a1d + N_NODES * 4;                   // [176*4]
  float* wad4   = was4 + IN_DIM * 4;                   // [176*4]
  float* pooled = wad4 + IN_DIM * 4;                   // [G,128]
  int* indptr = (int*)(pooled + N_GRAPHS * HID);       // [N+1]
  int* cnt    = indptr + (N_NODES + 1);                // [N]   (zeroed)
  int* cursor = cnt + N_NODES;                         // [N]   (zeroed)
  float* a2s  = (float*)(cursor + N_NODES);            // [N]   (zeroed)
  float* a2d  = a2s + N_NODES;                         // [N]   (zeroed)
  int* srcs   = (int*)(a2d + N_NODES);                 // [E+N]
  int* gstarts= srcs + TOT_EDGES;                      // [G+1]
  float* xw2  = h;  // alias: h dead after last agg1h; xw2 [N,128] fits in h [N,176]

  // zero cnt, cursor, a2s, a2d in one shot (contiguous)
  hipMemsetAsync(cnt, 0, 4 * N_NODES * sizeof(int), stream);

  const int NB4 = (N_NODES + 3) / 4;
  feats_ln_kernel<<<NB4, 256, 0, stream>>>(
      x_scalar, x_opcode, x_source, x_sink, x_string, x_payload,
      emb_opcode, emb_source, emb_sink, emb_string, emb_payload,
      ln_gamma, ln_beta, h);

  int nthreads = TOT_EDGES;
  count_kernel<<<(nthreads + 255) / 256, 256, 0, stream>>>(edge_index, cnt, N_EDGES, N_NODES);
  prefix_kernel<<<1, 256, 0, stream>>>(cnt, indptr, N_NODES, TOT_EDGES);
  scatter_kernel<<<(nthreads + 255) / 256, 256, 0, stream>>>(edge_index, indptr, cursor, srcs, N_EDGES, N_NODES);

  wasd_kernel<<<(IN_DIM + 3) / 4, 256, 0, stream>>>(W1, att_src1, att_dst1, was4, wad4);

  att1h_kernel<<<NB4, 256, 0, stream>>>(h, was4, wad4, a1s, a1d);

  for (int n0 = 0; n0 < N_NODES; n0 += chunk) {
    int nM = min(chunk, N_NODES - n0);
    agg1h_kernel<<<(nM + 3) / 4, 256, 0, stream>>>(h, a1s, a1d, indptr, srcs, aggh, n0, nM);
    gemm_head_kernel<<<dim3((nM + 63) / 64, 1, 4), 256, 0, stream>>>(
        aggh, W1, b1, out1, nM, n0);
  }

  // GEMM2 + fused att2 logits: xw2 = out1@W2, a2s/a2d accumulated per row.
  gemm2att_kernel<<<dim3(2, (N_NODES + 63) / 64), 256, 0, stream>>>(
      out1, W2, att_src2, att_dst2, xw2, a2s, a2d, N_NODES);

  agg2_kernel<<<NB4, 256, 0, stream>>>(xw2, a2s, a2d, indptr, srcs, b2, out2);

  gstart_kernel<<<1, 128, 0, stream>>>(batch, gstarts, N_NODES, N_GRAPHS);
  pool_kernel<<<N_GRAPHS, HID, 0, stream>>>(out2, gstarts, pooled);
  cls_kernel<<<N_GRAPHS, HID, 0, stream>>>(pooled, cls_w1, cls_b1, cls_w2, cls_b2, (float*)d_out);
}